// Round 14
// baseline (224.243 us; speedup 1.0000x reference)
//
#include <hip/hip_runtime.h>
#include <math.h>

#define T_STEPS 16
#define NTOK 2048
#define WAVES_PER_BLOCK 8
#define BLOCK (WAVES_PER_BLOCK * 64)
#define NUNIT 16   // unit j covers token blocks 2j (lo half) and 2j+1 (hi half)

typedef _Float16 h2 __attribute__((ext_vector_type(2)));
typedef unsigned short us2 __attribute__((ext_vector_type(2)));
#define BC(T, x) __builtin_bit_cast(T, x)

__device__ __forceinline__ h2 splat16(float v) {
    h2 r; r.x = (_Float16)v; r.y = r.x; return r;
}

template<int CTRL>
__device__ __forceinline__ unsigned dpp_u32(unsigned v) {
    return (unsigned)__builtin_amdgcn_update_dpp((int)v, (int)v, CTRL, 0xf, 0xf, false);
}

// 64-lane u32 min via DPP (row_shr 1/2/4/8 + row_bcast15/31) + readlane 63
__device__ __forceinline__ unsigned wave_min_u32(unsigned v) {
    unsigned t;
    t = dpp_u32<0x111>(v); v = t < v ? t : v;
    t = dpp_u32<0x112>(v); v = t < v ? t : v;
    t = dpp_u32<0x114>(v); v = t < v ? t : v;
    t = dpp_u32<0x118>(v); v = t < v ? t : v;
    t = dpp_u32<0x142>(v); v = t < v ? t : v;
    t = dpp_u32<0x143>(v); v = t < v ? t : v;
    return (unsigned)__builtin_amdgcn_readlane((int)v, 63);
}

// 64-lane packed-u16 elementwise min via DPP; returns min of both halves
__device__ __forceinline__ unsigned wave_min_pk_u16(us2 v) {
#define STEPD(C) { const us2 t_ = BC(us2, dpp_u32<C>(BC(unsigned, v))); \
                   v = __builtin_elementwise_min(v, t_); }
    STEPD(0x111) STEPD(0x112) STEPD(0x114) STEPD(0x118) STEPD(0x142) STEPD(0x143)
#undef STEPD
    const unsigned r = (unsigned)__builtin_amdgcn_readlane((int)BC(unsigned, v), 63);
    const unsigned lo = r & 0xffffu, hi = r >> 16;
    return lo < hi ? lo : hi;
}

// polynomial atan2, |err| ~1e-4 rad; heading is output-only (carry uses edge)
__device__ __forceinline__ float fast_atan2(float y, float x) {
    const float ax = fabsf(x), ay = fabsf(y);
    const float mx = fmaxf(ax, ay), mn = fminf(ax, ay);
    const float a = mn / mx;
    const float s = a * a;
    float r = fmaf(fmaf(fmaf(-0.0464964749f, s, 0.15931422f), s, -0.327622764f), s * a, a);
    if (ay > ax) r = 1.57079637f - r;
    if (x < 0.f) r = 3.14159274f - r;
    return y < 0.f ? -r : r;
}

// pass 1, one unit = blocks {2j, 2j+1}: 2 ds_read_b128 + 17 packed VALU.
// sigma = sum of 4 SQUARED corner distances (packed f16, no sqrt at all).
// Sound filter bracket (exact math): sqrt(sigma) <= d <= 2*sqrt(sigma)
//  => argmin(d) is always in { sigma <= 4*sigma_min } (4.5 covers f16 rounding).
#define PASS1(j, pk) { \
    const int sl = ((j) << 6) | lane; \
    const uint4 E0 = ldsP0[sl]; \
    const uint4 E1 = ldsP1[sl]; \
    h2 dx = BC(h2, E0.x) + ux0, dy = BC(h2, E0.y) + uy0; \
    h2 sg = dx * dx;      sg = dy * dy + sg; \
    dx = BC(h2, E0.z) + ux1; dy = BC(h2, E0.w) + uy1; \
    sg = dx * dx + sg;    sg = dy * dy + sg; \
    dx = BC(h2, E1.x) + ux2; dy = BC(h2, E1.y) + uy2; \
    sg = dx * dx + sg;    sg = dy * dy + sg; \
    dx = BC(h2, E1.z) + ux3; dy = BC(h2, E1.w) + uy3; \
    sg = dx * dx + sg;    sg = dy * dy + sg; \
    pk = BC(unsigned, sg); \
    pmin = __builtin_elementwise_min(pmin, BC(us2, sg)); \
    if ((j) & 1) __builtin_amdgcn_sched_barrier(0); }

// candidate-mask: integer compare on positive f16 bit patterns (monotone)
#define MASK(j, pk) { \
    if ((pk & 0xffffu) <= tb32) cmask |= (1u << (2*(j))); \
    if ((pk >> 16)     <= tb32) cmask |= (1u << (2*(j)+1)); }

#define FOR_U(M) \
    M(0,pk00)  M(1,pk01)  M(2,pk02)  M(3,pk03)  M(4,pk04)  M(5,pk05)  M(6,pk06)  M(7,pk07) \
    M(8,pk08)  M(9,pk09)  M(10,pk10) M(11,pk11) M(12,pk12) M(13,pk13) M(14,pk14) M(15,pk15)

#define DECL_U(j, pk) unsigned pk;

__global__ __launch_bounds__(BLOCK)
void tokenizer_kernel(const float* __restrict__ data,
                      const float* __restrict__ tok,
                      float* __restrict__ out,
                      int B) {
    // f16 codebook only: 32 KB -> 4 blocks/CU (LDS-limited), 8 waves/SIMD
    __shared__ uint4 ldsP0[NUNIT * 64];   // corners 0,1: {x0pk,y0pk,x1pk,y1pk}
    __shared__ uint4 ldsP1[NUNIT * 64];   // corners 2,3
    __shared__ float4 s_step[WAVES_PER_BLOCK][T_STEPS];  // px, py, sin, cos

    const float4* gsrc = (const float4*)tok;
    for (int slot = threadIdx.x; slot < NUNIT * 64; slot += BLOCK) {
        const int j = slot >> 6, l = slot & 63;
        const int n0 = ((2 * j) << 6) | l, n1 = n0 + 64;
        const float4 a0 = gsrc[2 * n0], b0 = gsrc[2 * n0 + 1];
        const float4 a1 = gsrc[2 * n1], b1 = gsrc[2 * n1 + 1];
        uint4 e0, e1;
        e0.x = BC(unsigned, __builtin_amdgcn_cvt_pkrtz(a0.x, a1.x));
        e0.y = BC(unsigned, __builtin_amdgcn_cvt_pkrtz(a0.y, a1.y));
        e0.z = BC(unsigned, __builtin_amdgcn_cvt_pkrtz(a0.z, a1.z));
        e0.w = BC(unsigned, __builtin_amdgcn_cvt_pkrtz(a0.w, a1.w));
        e1.x = BC(unsigned, __builtin_amdgcn_cvt_pkrtz(b0.x, b1.x));
        e1.y = BC(unsigned, __builtin_amdgcn_cvt_pkrtz(b0.y, b1.y));
        e1.z = BC(unsigned, __builtin_amdgcn_cvt_pkrtz(b0.z, b1.z));
        e1.w = BC(unsigned, __builtin_amdgcn_cvt_pkrtz(b0.w, b1.w));
        ldsP0[slot] = e0;
        ldsP1[slot] = e1;
    }

    const int wave = threadIdx.x >> 6;
    const int lane = threadIdx.x & 63;
    const int b = blockIdx.x * WAVES_PER_BLOCK + wave;
    const float* db = data + (size_t)b * (T_STEPS * 3);

    // hoisted per-step trig: 16 lanes compute the 16 steps' sincos in parallel
    if (b < B && lane < T_STEPS) {
        const float px = db[lane * 3 + 0];
        const float py = db[lane * 3 + 1];
        const float hh = db[lane * 3 + 2];
        float s_, c_;
        sincosf(hh, &s_, &c_);
        s_step[wave][lane] = make_float4(px, py, s_, c_);
    }
    __syncthreads();

    if (b >= B) return;

    float* outIdx  = out;
    float* outPos  = out + (size_t)B * T_STEPS;
    float* outHead = out + (size_t)B * T_STEPS * 3;

    float cpx = 0.f, cpy = 0.f;    // carry: prev_pos
    float rc = 1.f, rs = 0.f;      // carry: cos/sin(prev_head)

    for (int t = 0; t < T_STEPS; ++t) {
        const float4 st = s_step[wave][t];
        const float px = st.x, py = st.y, sh = st.z, ch = st.w;

        const float hc = 0.5f * ch, hs = 0.5f * sh;
        const float lc = 4.8f * hc, ls = 4.8f * hs;
        const float wc = 2.0f * hc, ws = 2.0f * hs;

        // e_j = cp - g_j ; u_j = R^T e_j  =>  dist_j = || f_j + u_j ||
        const float e0x = cpx - (px + lc - ws), e0y = cpy - (py + ls + wc);
        const float e1x = cpx - (px + lc + ws), e1y = cpy - (py + ls - wc);
        const float e2x = cpx - (px - lc + ws), e2y = cpy - (py - ls - wc);
        const float e3x = cpx - (px - lc - ws), e3y = cpy - (py - ls + wc);
        const float u0x = rc * e0x + rs * e0y, u0y = rc * e0y - rs * e0x;
        const float u1x = rc * e1x + rs * e1y, u1y = rc * e1y - rs * e1x;
        const float u2x = rc * e2x + rs * e2y, u2y = rc * e2y - rs * e2x;
        const float u3x = rc * e3x + rs * e3y, u3y = rc * e3y - rs * e3x;

        // packed-f16 u vectors (same u in both halves of a unit)
        const h2 ux0 = splat16(u0x), uy0 = splat16(u0y);
        const h2 ux1 = splat16(u1x), uy1 = splat16(u1y);
        const h2 ux2 = splat16(u2x), uy2 = splat16(u2y);
        const h2 ux3 = splat16(u3x), uy3 = splat16(u3y);

        // ---- pass 1: packed sum-of-squares sigma (17 ops/unit, sqrt-free)
        FOR_U(DECL_U)
        us2 pmin; pmin.x = (unsigned short)0x7fff; pmin.y = (unsigned short)0x7fff;
        FOR_U(PASS1)

        // wave-wide min of sigma via DPP
        const unsigned dm16 = wave_min_pk_u16(pmin);
        const float sminf = (float)BC(_Float16, (unsigned short)dm16);
        // exact bracket needs 4.0; 4.5 + 0.125 covers f16 rounding both sides
        const float thrf = fmaf(sminf, 4.5f, 0.125f);
        const unsigned tb32 =
            (unsigned)BC(unsigned short, (_Float16)thrf) + 1u;

        // ---- pass 2: per-lane candidate bitmask; exact f32 eval from global
        unsigned cmask = 0u;
        FOR_U(MASK)

        float bestd = 3.4e38f;
        int   bestn = 0x7fffffff;
        unsigned m = cmask;
        while (__any(m != 0u)) {
            if (m) {
                const int k = __builtin_ctz(m);
                m &= (m - 1u);
                const int n = (k << 6) | lane;
                const float4 A  = gsrc[2 * n];
                const float4 Bv = gsrc[2 * n + 1];
                float dx, dy;
                dx = A.x  + u0x; dy = A.y  + u0y; const float q0 = fmaf(dy, dy, dx * dx);
                dx = A.z  + u1x; dy = A.w  + u1y; const float q1 = fmaf(dy, dy, dx * dx);
                dx = Bv.x + u2x; dy = Bv.y + u2y; const float q2 = fmaf(dy, dy, dx * dx);
                dx = Bv.z + u3x; dy = Bv.w + u3y; const float q3 = fmaf(dy, dy, dx * dx);
                const float d = (__builtin_amdgcn_sqrtf(q0) + __builtin_amdgcn_sqrtf(q1)) +
                                (__builtin_amdgcn_sqrtf(q2) + __builtin_amdgcn_sqrtf(q3));
                const bool upd = (d < bestd) || (d == bestd && n < bestn);
                bestd = upd ? d : bestd;
                bestn = upd ? n : bestn;
            }
        }

        // exact argmin across wave: DPP min on d-bits, then lowest index among minima
        const unsigned dbits = BC(unsigned, bestd);
        const unsigned dminb = wave_min_u32(dbits);
        const unsigned candn = (dbits == dminb) ? (unsigned)bestn : 0x7fffffffu;
        const int nSel = (int)wave_min_u32(candn);

        // selected contour in global frame (exact f32 codebook from L2)
        const float4 A  = gsrc[2 * nSel];
        const float4 Bv = gsrc[2 * nSel + 1];
        const float c0x = A.x  * rc - A.y  * rs + cpx, c0y = A.x  * rs + A.y  * rc + cpy;
        const float c1x = A.z  * rc - A.w  * rs + cpx, c1y = A.z  * rs + A.w  * rc + cpy;
        const float c2x = Bv.x * rc - Bv.y * rs + cpx, c2y = Bv.x * rs + Bv.y * rc + cpy;
        const float c3x = Bv.z * rc - Bv.w * rs + cpx, c3y = Bv.z * rs + Bv.w * rc + cpy;

        const float npx = 0.25f * (((c0x + c1x) + c2x) + c3x);
        const float npy = 0.25f * (((c0y + c1y) + c2y) + c3y);
        const float dxx = c0x - c3x, dyy = c0y - c3y;

        // carry FIRST (critical path into next step's scan)
        cpx = npx; cpy = npy;
        const float inv = __builtin_amdgcn_rsqf(fmaf(dyy, dyy, dxx * dxx));
        rc = dxx * inv;
        rs = dyy * inv;

        if (lane == 0) {
            const int ot = b * T_STEPS + t;
            outIdx[ot]         = (float)nSel;
            outPos[2 * ot]     = npx;
            outPos[2 * ot + 1] = npy;
            outHead[ot]        = fast_atan2(dyy, dxx);
        }
    }
}

extern "C" void kernel_launch(void* const* d_in, const int* in_sizes, int n_in,
                              void* d_out, int out_size, void* d_ws, size_t ws_size,
                              hipStream_t stream) {
    const float* data = (const float*)d_in[0];
    const float* tok  = (const float*)d_in[1];
    float* out = (float*)d_out;

    const int B = in_sizes[0] / (T_STEPS * 3);   // 4096
    const int grid = (B + WAVES_PER_BLOCK - 1) / WAVES_PER_BLOCK;

    tokenizer_kernel<<<grid, BLOCK, 0, stream>>>(data, tok, out, B);
}

// Round 16
// 102.679 us; speedup vs baseline: 2.1839x; 2.1839x over previous
//
#include <hip/hip_runtime.h>
#include <math.h>

#define T_STEPS 16
#define NTOK 2048
#define WAVES_PER_BLOCK 8
#define BLOCK (WAVES_PER_BLOCK * 64)
#define NUNIT 16   // unit j covers token blocks 2j (lo half) and 2j+1 (hi half)

typedef _Float16 h2 __attribute__((ext_vector_type(2)));
typedef unsigned short us2 __attribute__((ext_vector_type(2)));
#define BC(T, x) __builtin_bit_cast(T, x)

__device__ __forceinline__ h2 splat16(float v) {
    h2 r; r.x = (_Float16)v; r.y = r.x; return r;
}

template<int CTRL>
__device__ __forceinline__ unsigned dpp_u32(unsigned v) {
    return (unsigned)__builtin_amdgcn_update_dpp((int)v, (int)v, CTRL, 0xf, 0xf, false);
}

// 64-lane u32 min via DPP (row_shr 1/2/4/8 + row_bcast15/31) + readlane 63
__device__ __forceinline__ unsigned wave_min_u32(unsigned v) {
    unsigned t;
    t = dpp_u32<0x111>(v); v = t < v ? t : v;
    t = dpp_u32<0x112>(v); v = t < v ? t : v;
    t = dpp_u32<0x114>(v); v = t < v ? t : v;
    t = dpp_u32<0x118>(v); v = t < v ? t : v;
    t = dpp_u32<0x142>(v); v = t < v ? t : v;
    t = dpp_u32<0x143>(v); v = t < v ? t : v;
    return (unsigned)__builtin_amdgcn_readlane((int)v, 63);
}

// 64-lane packed-u16 elementwise min via DPP; returns min of both halves
__device__ __forceinline__ unsigned wave_min_pk_u16(us2 v) {
#define STEPD(C) { const us2 t_ = BC(us2, dpp_u32<C>(BC(unsigned, v))); \
                   v = __builtin_elementwise_min(v, t_); }
    STEPD(0x111) STEPD(0x112) STEPD(0x114) STEPD(0x118) STEPD(0x142) STEPD(0x143)
#undef STEPD
    const unsigned r = (unsigned)__builtin_amdgcn_readlane((int)BC(unsigned, v), 63);
    const unsigned lo = r & 0xffffu, hi = r >> 16;
    return lo < hi ? lo : hi;
}

// polynomial atan2, |err| ~1e-4 rad; heading is output-only (carry uses edge)
__device__ __forceinline__ float fast_atan2(float y, float x) {
    const float ax = fabsf(x), ay = fabsf(y);
    const float mx = fmaxf(ax, ay), mn = fminf(ax, ay);
    const float a = mn / mx;
    const float s = a * a;
    float r = fmaf(fmaf(fmaf(-0.0464964749f, s, 0.15931422f), s, -0.327622764f), s * a, a);
    if (ay > ax) r = 1.57079637f - r;
    if (x < 0.f) r = 3.14159274f - r;
    return y < 0.f ? -r : r;
}

// One corner, two token-blocks at once — 6 compiler-packed ops (PROVEN
// correct in R13, absmax 0.015625): dx,dy adds; q = dx*dx + dy*dy (pk fma);
// sqrt bit-hack PER-HALF via ext-vector us2 shift (compiler emits
// v_pk_lshrrev_b16 with a properly replicated shift constant — hand-asm
// with inline `1` shifted only the LOW half: R15's failure).
__device__ __forceinline__ h2 corner16v(unsigned Ex, unsigned Ey, h2 ux, h2 uy) {
    const h2 dx = BC(h2, Ex) + ux;
    const h2 dy = BC(h2, Ey) + uy;
    const h2 q  = dx * dx + dy * dy;
    us2 bq = BC(us2, q);
    bq = (bq >> 1) + (us2){(unsigned short)0x1de9, (unsigned short)0x1de9};
    return BC(h2, bq);
}

// pass 1, one unit = blocks {2j, 2j+1}: 2 ds_read_b128 + 28 packed VALU.
// sched_barrier every 2nd unit (R12 cadence): pins VGPR low -> 8 waves/SIMD.
// (R13 without it: scheduler hoisted loads, VGPR 88, occupancy halved.)
#define PASS1(j, pk) { \
    const int sl = ((j) << 6) | lane; \
    const uint4 E0 = ldsP0[sl]; \
    const uint4 E1 = ldsP1[sl]; \
    const h2 s01 = corner16v(E0.x, E0.y, ux0, uy0) + corner16v(E0.z, E0.w, ux1, uy1); \
    const h2 s23 = corner16v(E1.x, E1.y, ux2, uy2) + corner16v(E1.z, E1.w, ux3, uy3); \
    const h2 dt = s01 + s23; \
    pk = BC(unsigned, dt); \
    pmin = __builtin_elementwise_min(pmin, BC(us2, dt)); \
    if ((j) & 1) __builtin_amdgcn_sched_barrier(0); }

// candidate-mask: integer compare on positive f16 bit patterns (monotone)
#define MASK(j, pk) { \
    if ((pk & 0xffffu) <= tb32) cmask |= (1u << (2*(j))); \
    if ((pk >> 16)     <= tb32) cmask |= (1u << (2*(j)+1)); }

#define FOR_U(M) \
    M(0,pk00)  M(1,pk01)  M(2,pk02)  M(3,pk03)  M(4,pk04)  M(5,pk05)  M(6,pk06)  M(7,pk07) \
    M(8,pk08)  M(9,pk09)  M(10,pk10) M(11,pk11) M(12,pk12) M(13,pk13) M(14,pk14) M(15,pk15)

#define DECL_U(j, pk) unsigned pk;

__global__ __launch_bounds__(BLOCK)
void tokenizer_kernel(const float* __restrict__ data,
                      const float* __restrict__ tok,
                      float* __restrict__ out,
                      int B) {
    // f16 codebook only: 32 KB -> 4 blocks/CU, 8 waves/SIMD
    __shared__ uint4 ldsP0[NUNIT * 64];   // corners 0,1: {x0pk,y0pk,x1pk,y1pk}
    __shared__ uint4 ldsP1[NUNIT * 64];   // corners 2,3
    __shared__ float4 s_step[WAVES_PER_BLOCK][T_STEPS];  // px, py, sin, cos

    const float4* gsrc = (const float4*)tok;
    for (int slot = threadIdx.x; slot < NUNIT * 64; slot += BLOCK) {
        const int j = slot >> 6, l = slot & 63;
        const int n0 = ((2 * j) << 6) | l, n1 = n0 + 64;
        const float4 a0 = gsrc[2 * n0], b0 = gsrc[2 * n0 + 1];
        const float4 a1 = gsrc[2 * n1], b1 = gsrc[2 * n1 + 1];
        uint4 e0, e1;
        e0.x = BC(unsigned, __builtin_amdgcn_cvt_pkrtz(a0.x, a1.x));
        e0.y = BC(unsigned, __builtin_amdgcn_cvt_pkrtz(a0.y, a1.y));
        e0.z = BC(unsigned, __builtin_amdgcn_cvt_pkrtz(a0.z, a1.z));
        e0.w = BC(unsigned, __builtin_amdgcn_cvt_pkrtz(a0.w, a1.w));
        e1.x = BC(unsigned, __builtin_amdgcn_cvt_pkrtz(b0.x, b1.x));
        e1.y = BC(unsigned, __builtin_amdgcn_cvt_pkrtz(b0.y, b1.y));
        e1.z = BC(unsigned, __builtin_amdgcn_cvt_pkrtz(b0.z, b1.z));
        e1.w = BC(unsigned, __builtin_amdgcn_cvt_pkrtz(b0.w, b1.w));
        ldsP0[slot] = e0;
        ldsP1[slot] = e1;
    }

    const int wave = threadIdx.x >> 6;
    const int lane = threadIdx.x & 63;
    const int b = blockIdx.x * WAVES_PER_BLOCK + wave;
    const float* db = data + (size_t)b * (T_STEPS * 3);

    // hoisted per-step trig: 16 lanes compute the 16 steps' sincos in parallel
    if (b < B && lane < T_STEPS) {
        const float px = db[lane * 3 + 0];
        const float py = db[lane * 3 + 1];
        const float hh = db[lane * 3 + 2];
        float s_, c_;
        sincosf(hh, &s_, &c_);
        s_step[wave][lane] = make_float4(px, py, s_, c_);
    }
    __syncthreads();

    if (b >= B) return;

    float* outIdx  = out;
    float* outPos  = out + (size_t)B * T_STEPS;
    float* outHead = out + (size_t)B * T_STEPS * 3;

    float cpx = 0.f, cpy = 0.f;    // carry: prev_pos
    float rc = 1.f, rs = 0.f;      // carry: cos/sin(prev_head)

    for (int t = 0; t < T_STEPS; ++t) {
        const float4 st = s_step[wave][t];
        const float px = st.x, py = st.y, sh = st.z, ch = st.w;

        const float hc = 0.5f * ch, hs = 0.5f * sh;
        const float lc = 4.8f * hc, ls = 4.8f * hs;
        const float wc = 2.0f * hc, ws = 2.0f * hs;

        // e_j = cp - g_j ; u_j = R^T e_j  =>  dist_j = || f_j + u_j ||
        const float e0x = cpx - (px + lc - ws), e0y = cpy - (py + ls + wc);
        const float e1x = cpx - (px + lc + ws), e1y = cpy - (py + ls - wc);
        const float e2x = cpx - (px - lc + ws), e2y = cpy - (py - ls - wc);
        const float e3x = cpx - (px - lc - ws), e3y = cpy - (py - ls + wc);
        const float u0x = rc * e0x + rs * e0y, u0y = rc * e0y - rs * e0x;
        const float u1x = rc * e1x + rs * e1y, u1y = rc * e1y - rs * e1x;
        const float u2x = rc * e2x + rs * e2y, u2y = rc * e2y - rs * e2x;
        const float u3x = rc * e3x + rs * e3y, u3y = rc * e3y - rs * e3x;

        // packed-f16 u vectors (same u in both halves of a unit)
        const h2 ux0 = splat16(u0x), uy0 = splat16(u0y);
        const h2 ux1 = splat16(u1x), uy1 = splat16(u1y);
        const h2 ux2 = splat16(u2x), uy2 = splat16(u2y);
        const h2 ux3 = splat16(u3x), uy3 = splat16(u3y);

        // ---- pass 1: compiler-packed approx d~, 2 blocks per lane-op
        FOR_U(DECL_U)
        us2 pmin; pmin.x = (unsigned short)0x7fff; pmin.y = (unsigned short)0x7fff;
        FOR_U(PASS1)

        // wave-wide min via DPP
        const unsigned dm16 = wave_min_pk_u16(pmin);
        const float dminf = (float)BC(_Float16, (unsigned short)dm16);
        // slack: hack err [-1.1%,+4.5%] + f16 rounding; alpha=1.13 covers
        // eps<=6.1% rel, beta=0.18 covers abs input-rounding slack
        const float thrf = fmaf(dminf, 1.13f, 0.18f);
        const unsigned tb32 =
            (unsigned)BC(unsigned short, (_Float16)thrf) + 1u;

        // ---- pass 2: per-lane candidate bitmask; exact f32 eval from global
        unsigned cmask = 0u;
        FOR_U(MASK)

        float bestd = 3.4e38f;
        int   bestn = 0x7fffffff;
        unsigned m = cmask;
        while (__any(m != 0u)) {
            if (m) {
                const int k = __builtin_ctz(m);
                m &= (m - 1u);
                const int n = (k << 6) | lane;
                const float4 A  = gsrc[2 * n];
                const float4 Bv = gsrc[2 * n + 1];
                float dx, dy;
                dx = A.x  + u0x; dy = A.y  + u0y; const float q0 = fmaf(dy, dy, dx * dx);
                dx = A.z  + u1x; dy = A.w  + u1y; const float q1 = fmaf(dy, dy, dx * dx);
                dx = Bv.x + u2x; dy = Bv.y + u2y; const float q2 = fmaf(dy, dy, dx * dx);
                dx = Bv.z + u3x; dy = Bv.w + u3y; const float q3 = fmaf(dy, dy, dx * dx);
                const float d = (__builtin_amdgcn_sqrtf(q0) + __builtin_amdgcn_sqrtf(q1)) +
                                (__builtin_amdgcn_sqrtf(q2) + __builtin_amdgcn_sqrtf(q3));
                const bool upd = (d < bestd) || (d == bestd && n < bestn);
                bestd = upd ? d : bestd;
                bestn = upd ? n : bestn;
            }
        }

        // exact argmin across wave: DPP min on d-bits, then lowest index among minima
        const unsigned dbits = BC(unsigned, bestd);
        const unsigned dminb = wave_min_u32(dbits);
        const unsigned candn = (dbits == dminb) ? (unsigned)bestn : 0x7fffffffu;
        const int nSel = (int)wave_min_u32(candn);

        // selected contour in global frame (exact f32 codebook from L2)
        const float4 A  = gsrc[2 * nSel];
        const float4 Bv = gsrc[2 * nSel + 1];
        const float c0x = A.x  * rc - A.y  * rs + cpx, c0y = A.x  * rs + A.y  * rc + cpy;
        const float c1x = A.z  * rc - A.w  * rs + cpx, c1y = A.z  * rs + A.w  * rc + cpy;
        const float c2x = Bv.x * rc - Bv.y * rs + cpx, c2y = Bv.x * rs + Bv.y * rc + cpy;
        const float c3x = Bv.z * rc - Bv.w * rs + cpx, c3y = Bv.z * rs + Bv.w * rc + cpy;

        const float npx = 0.25f * (((c0x + c1x) + c2x) + c3x);
        const float npy = 0.25f * (((c0y + c1y) + c2y) + c3y);
        const float dxx = c0x - c3x, dyy = c0y - c3y;

        // carry FIRST (critical path into next step's scan)
        cpx = npx; cpy = npy;
        const float inv = __builtin_amdgcn_rsqf(fmaf(dyy, dyy, dxx * dxx));
        rc = dxx * inv;
        rs = dyy * inv;

        if (lane == 0) {
            const int ot = b * T_STEPS + t;
            outIdx[ot]         = (float)nSel;
            outPos[2 * ot]     = npx;
            outPos[2 * ot + 1] = npy;
            outHead[ot]        = fast_atan2(dyy, dxx);
        }
    }
}

extern "C" void kernel_launch(void* const* d_in, const int* in_sizes, int n_in,
                              void* d_out, int out_size, void* d_ws, size_t ws_size,
                              hipStream_t stream) {
    const float* data = (const float*)d_in[0];
    const float* tok  = (const float*)d_in[1];
    float* out = (float*)d_out;

    const int B = in_sizes[0] / (T_STEPS * 3);   // 4096
    const int grid = (B + WAVES_PER_BLOCK - 1) / WAVES_PER_BLOCK;

    tokenizer_kernel<<<grid, BLOCK, 0, stream>>>(data, tok, out, B);
}

// Round 17
// 99.849 us; speedup vs baseline: 2.2458x; 1.0283x over previous
//
#include <hip/hip_runtime.h>
#include <math.h>

#define T_STEPS 16
#define NTOK 2048
#define WAVES_PER_BLOCK 8
#define BLOCK (WAVES_PER_BLOCK * 64)
#define NUNIT 16   // unit j covers token blocks 2j (lo half) and 2j+1 (hi half)

typedef _Float16 h2 __attribute__((ext_vector_type(2)));
typedef unsigned short us2 __attribute__((ext_vector_type(2)));
#define BC(T, x) __builtin_bit_cast(T, x)

__device__ __forceinline__ h2 splat16(float v) {
    h2 r; r.x = (_Float16)v; r.y = r.x; return r;
}

template<int CTRL>
__device__ __forceinline__ unsigned dpp_u32(unsigned v) {
    return (unsigned)__builtin_amdgcn_update_dpp((int)v, (int)v, CTRL, 0xf, 0xf, false);
}

// 64-lane u32 min via DPP (row_shr 1/2/4/8 + row_bcast15/31) + readlane 63
__device__ __forceinline__ unsigned wave_min_u32(unsigned v) {
    unsigned t;
    t = dpp_u32<0x111>(v); v = t < v ? t : v;
    t = dpp_u32<0x112>(v); v = t < v ? t : v;
    t = dpp_u32<0x114>(v); v = t < v ? t : v;
    t = dpp_u32<0x118>(v); v = t < v ? t : v;
    t = dpp_u32<0x142>(v); v = t < v ? t : v;
    t = dpp_u32<0x143>(v); v = t < v ? t : v;
    return (unsigned)__builtin_amdgcn_readlane((int)v, 63);
}

// 64-lane packed-u16 elementwise min via DPP; returns min of both halves
__device__ __forceinline__ unsigned wave_min_pk_u16(us2 v) {
#define STEPD(C) { const us2 t_ = BC(us2, dpp_u32<C>(BC(unsigned, v))); \
                   v = __builtin_elementwise_min(v, t_); }
    STEPD(0x111) STEPD(0x112) STEPD(0x114) STEPD(0x118) STEPD(0x142) STEPD(0x143)
#undef STEPD
    const unsigned r = (unsigned)__builtin_amdgcn_readlane((int)BC(unsigned, v), 63);
    const unsigned lo = r & 0xffffu, hi = r >> 16;
    return lo < hi ? lo : hi;
}

// polynomial atan2, |err| ~1e-4 rad; heading is output-only (carry uses edge)
__device__ __forceinline__ float fast_atan2(float y, float x) {
    const float ax = fabsf(x), ay = fabsf(y);
    const float mx = fmaxf(ax, ay), mn = fminf(ax, ay);
    const float a = mn / mx;
    const float s = a * a;
    float r = fmaf(fmaf(fmaf(-0.0464964749f, s, 0.15931422f), s, -0.327622764f), s * a, a);
    if (ay > ax) r = 1.57079637f - r;
    if (x < 0.f) r = 3.14159274f - r;
    return y < 0.f ? -r : r;
}

// One corner, two token-blocks at once — 6 compiler-packed ops (PROVEN R13/R16,
// absmax 0.015625): dx,dy adds; q = dx*dx + dy*dy; sqrt bit-hack per half.
__device__ __forceinline__ h2 corner16v(unsigned Ex, unsigned Ey, h2 ux, h2 uy) {
    const h2 dx = BC(h2, Ex) + ux;
    const h2 dy = BC(h2, Ey) + uy;
    const h2 q  = dx * dx + dy * dy;
    us2 bq = BC(us2, q);
    bq = (bq >> 1) + (us2){(unsigned short)0x1de9, (unsigned short)0x1de9};
    return BC(h2, bq);
}

// pass 1, one unit = blocks {2j, 2j+1}: 2 ds_read_b128 + 28 packed VALU.
// sched_barrier every 2nd unit (R12/R16 cadence): pins VGPR low -> 8 waves/SIMD.
#define PASS1(j, pk) { \
    const int sl = ((j) << 6) | lane; \
    const uint4 E0 = ldsP0[sl]; \
    const uint4 E1 = ldsP1[sl]; \
    const h2 s01 = corner16v(E0.x, E0.y, ux0, uy0) + corner16v(E0.z, E0.w, ux1, uy1); \
    const h2 s23 = corner16v(E1.x, E1.y, ux2, uy2) + corner16v(E1.z, E1.w, ux3, uy3); \
    const h2 dt = s01 + s23; \
    pk = BC(unsigned, dt); \
    pmin = __builtin_elementwise_min(pmin, BC(us2, dt)); \
    if ((j) & 1) __builtin_amdgcn_sched_barrier(0); }

// candidate-mask, packed sign-bit build (3 ops/unit, replaces R16's ~6):
// df = pk - thr2 per half (wrap-safe: both < 0x8000); sign bit = candidate.
// mm accumulates: unit j's lo flag -> bit j, hi flag -> bit 16+j (insert at
// 15/31, shift right once per unit; hi bits never reach the lo field).
#define MASKP(j, pk) { \
    const unsigned df = BC(unsigned, BC(us2, pk) - thr2v); \
    mm = (mm >> 1) | (df & 0x80008000u); }

#define FOR_U(M) \
    M(0,pk00)  M(1,pk01)  M(2,pk02)  M(3,pk03)  M(4,pk04)  M(5,pk05)  M(6,pk06)  M(7,pk07) \
    M(8,pk08)  M(9,pk09)  M(10,pk10) M(11,pk11) M(12,pk12) M(13,pk13) M(14,pk14) M(15,pk15)

#define DECL_U(j, pk) unsigned pk;

__global__ __launch_bounds__(BLOCK)
void tokenizer_kernel(const float* __restrict__ data,
                      const float* __restrict__ tok,
                      float* __restrict__ out,
                      int B) {
    // f16 codebook only: 32 KB
    __shared__ uint4 ldsP0[NUNIT * 64];   // corners 0,1: {x0pk,y0pk,x1pk,y1pk}
    __shared__ uint4 ldsP1[NUNIT * 64];   // corners 2,3
    __shared__ float4 s_step[WAVES_PER_BLOCK][T_STEPS];  // px, py, sin, cos

    const float4* gsrc = (const float4*)tok;
    for (int slot = threadIdx.x; slot < NUNIT * 64; slot += BLOCK) {
        const int j = slot >> 6, l = slot & 63;
        const int n0 = ((2 * j) << 6) | l, n1 = n0 + 64;
        const float4 a0 = gsrc[2 * n0], b0 = gsrc[2 * n0 + 1];
        const float4 a1 = gsrc[2 * n1], b1 = gsrc[2 * n1 + 1];
        uint4 e0, e1;
        e0.x = BC(unsigned, __builtin_amdgcn_cvt_pkrtz(a0.x, a1.x));
        e0.y = BC(unsigned, __builtin_amdgcn_cvt_pkrtz(a0.y, a1.y));
        e0.z = BC(unsigned, __builtin_amdgcn_cvt_pkrtz(a0.z, a1.z));
        e0.w = BC(unsigned, __builtin_amdgcn_cvt_pkrtz(a0.w, a1.w));
        e1.x = BC(unsigned, __builtin_amdgcn_cvt_pkrtz(b0.x, b1.x));
        e1.y = BC(unsigned, __builtin_amdgcn_cvt_pkrtz(b0.y, b1.y));
        e1.z = BC(unsigned, __builtin_amdgcn_cvt_pkrtz(b0.z, b1.z));
        e1.w = BC(unsigned, __builtin_amdgcn_cvt_pkrtz(b0.w, b1.w));
        ldsP0[slot] = e0;
        ldsP1[slot] = e1;
    }

    const int wave = threadIdx.x >> 6;
    const int lane = threadIdx.x & 63;
    const int b = blockIdx.x * WAVES_PER_BLOCK + wave;
    const float* db = data + (size_t)b * (T_STEPS * 3);

    // hoisted per-step trig: 16 lanes compute the 16 steps' sincos in parallel
    if (b < B && lane < T_STEPS) {
        const float px = db[lane * 3 + 0];
        const float py = db[lane * 3 + 1];
        const float hh = db[lane * 3 + 2];
        float s_, c_;
        sincosf(hh, &s_, &c_);
        s_step[wave][lane] = make_float4(px, py, s_, c_);
    }
    __syncthreads();

    if (b >= B) return;

    float* outIdx  = out;
    float* outPos  = out + (size_t)B * T_STEPS;
    float* outHead = out + (size_t)B * T_STEPS * 3;

    float cpx = 0.f, cpy = 0.f;    // carry: prev_pos
    float rc = 1.f, rs = 0.f;      // carry: cos/sin(prev_head)

    for (int t = 0; t < T_STEPS; ++t) {
        const float4 st = s_step[wave][t];
        const float px = st.x, py = st.y, sh = st.z, ch = st.w;

        const float hc = 0.5f * ch, hs = 0.5f * sh;
        const float lc = 4.8f * hc, ls = 4.8f * hs;
        const float wc = 2.0f * hc, ws = 2.0f * hs;

        // e_j = cp - g_j ; u_j = R^T e_j  =>  dist_j = || f_j + u_j ||
        const float e0x = cpx - (px + lc - ws), e0y = cpy - (py + ls + wc);
        const float e1x = cpx - (px + lc + ws), e1y = cpy - (py + ls - wc);
        const float e2x = cpx - (px - lc + ws), e2y = cpy - (py - ls - wc);
        const float e3x = cpx - (px - lc - ws), e3y = cpy - (py - ls + wc);
        const float u0x = rc * e0x + rs * e0y, u0y = rc * e0y - rs * e0x;
        const float u1x = rc * e1x + rs * e1y, u1y = rc * e1y - rs * e1x;
        const float u2x = rc * e2x + rs * e2y, u2y = rc * e2y - rs * e2x;
        const float u3x = rc * e3x + rs * e3y, u3y = rc * e3y - rs * e3x;

        // packed-f16 u vectors (same u in both halves of a unit)
        const h2 ux0 = splat16(u0x), uy0 = splat16(u0y);
        const h2 ux1 = splat16(u1x), uy1 = splat16(u1y);
        const h2 ux2 = splat16(u2x), uy2 = splat16(u2y);
        const h2 ux3 = splat16(u3x), uy3 = splat16(u3y);

        // ---- pass 1: compiler-packed approx d~, 2 blocks per lane-op
        FOR_U(DECL_U)
        us2 pmin; pmin.x = (unsigned short)0x7fff; pmin.y = (unsigned short)0x7fff;
        FOR_U(PASS1)

        // wave-wide min via DPP
        const unsigned dm16 = wave_min_pk_u16(pmin);
        const float dminf = (float)BC(_Float16, (unsigned short)dm16);
        // slack: hack err [-1.1%,+4.5%] + f16 rounding; alpha=1.13 covers
        // eps<=6.1% rel, beta=0.18 covers abs input-rounding slack
        const float thrf = fmaf(dminf, 1.13f, 0.18f);
        // R16 tested pk <= tb32 (tb32 = bits+1); sign test below is pk < thr_h,
        // so thr_h = bits+2 keeps the candidate set identical-or-superset.
        const unsigned short thr_h =
            (unsigned short)(BC(unsigned short, (_Float16)thrf) + 2);
        const us2 thr2v = {thr_h, thr_h};

        // ---- candidate mask: packed sign-bit accumulation (3 ops/unit)
        unsigned mm = 0u;
        FOR_U(MASKP)

        // ---- pass 2: per-lane bitmask; exact f32 eval from global (L2-hot)
        float bestd = 3.4e38f;
        int   bestn = 0x7fffffff;
        unsigned m = mm;
        while (__any(m != 0u)) {
            if (m) {
                const int bpos = __builtin_ctz(m);
                m &= (m - 1u);
                // bit b: b<16 -> block 2b (lo half); b>=16 -> block 2(b-16)+1
                const int k = ((bpos & 15) << 1) | (bpos >> 4);
                const int n = (k << 6) | lane;
                const float4 A  = gsrc[2 * n];
                const float4 Bv = gsrc[2 * n + 1];
                float dx, dy;
                dx = A.x  + u0x; dy = A.y  + u0y; const float q0 = fmaf(dy, dy, dx * dx);
                dx = A.z  + u1x; dy = A.w  + u1y; const float q1 = fmaf(dy, dy, dx * dx);
                dx = Bv.x + u2x; dy = Bv.y + u2y; const float q2 = fmaf(dy, dy, dx * dx);
                dx = Bv.z + u3x; dy = Bv.w + u3y; const float q3 = fmaf(dy, dy, dx * dx);
                const float d = (__builtin_amdgcn_sqrtf(q0) + __builtin_amdgcn_sqrtf(q1)) +
                                (__builtin_amdgcn_sqrtf(q2) + __builtin_amdgcn_sqrtf(q3));
                const bool upd = (d < bestd) || (d == bestd && n < bestn);
                bestd = upd ? d : bestd;
                bestn = upd ? n : bestn;
            }
        }

        // exact argmin across wave: DPP min on d-bits, then lowest index among minima
        const unsigned dbits = BC(unsigned, bestd);
        const unsigned dminb = wave_min_u32(dbits);
        const unsigned candn = (dbits == dminb) ? (unsigned)bestn : 0x7fffffffu;
        const int nSel = (int)wave_min_u32(candn);

        // selected contour in global frame (exact f32 codebook from L2)
        const float4 A  = gsrc[2 * nSel];
        const float4 Bv = gsrc[2 * nSel + 1];
        const float c0x = A.x  * rc - A.y  * rs + cpx, c0y = A.x  * rs + A.y  * rc + cpy;
        const float c1x = A.z  * rc - A.w  * rs + cpx, c1y = A.z  * rs + A.w  * rc + cpy;
        const float c2x = Bv.x * rc - Bv.y * rs + cpx, c2y = Bv.x * rs + Bv.y * rc + cpy;
        const float c3x = Bv.z * rc - Bv.w * rs + cpx, c3y = Bv.z * rs + Bv.w * rc + cpy;

        const float npx = 0.25f * (((c0x + c1x) + c2x) + c3x);
        const float npy = 0.25f * (((c0y + c1y) + c2y) + c3y);
        const float dxx = c0x - c3x, dyy = c0y - c3y;

        // carry FIRST (critical path into next step's scan)
        cpx = npx; cpy = npy;
        const float inv = __builtin_amdgcn_rsqf(fmaf(dyy, dyy, dxx * dxx));
        rc = dxx * inv;
        rs = dyy * inv;

        if (lane == 0) {
            const int ot = b * T_STEPS + t;
            outIdx[ot]         = (float)nSel;
            outPos[2 * ot]     = npx;
            outPos[2 * ot + 1] = npy;
            outHead[ot]        = fast_atan2(dyy, dxx);
        }
    }
}

extern "C" void kernel_launch(void* const* d_in, const int* in_sizes, int n_in,
                              void* d_out, int out_size, void* d_ws, size_t ws_size,
                              hipStream_t stream) {
    const float* data = (const float*)d_in[0];
    const float* tok  = (const float*)d_in[1];
    float* out = (float*)d_out;

    const int B = in_sizes[0] / (T_STEPS * 3);   // 4096
    const int grid = (B + WAVES_PER_BLOCK - 1) / WAVES_PER_BLOCK;

    tokenizer_kernel<<<grid, BLOCK, 0, stream>>>(data, tok, out, B);
}